// Round 2
// baseline (2003.399 us; speedup 1.0000x reference)
//
#include <hip/hip_runtime.h>
#include <hip/hip_bf16.h>

#define N_NODES 50000
#define N_EDGES 800000
#define DIM 128

// monotonic float<->uint encoding for atomicMax over signed floats
__device__ __forceinline__ unsigned fenc(float f){
  unsigned u = __float_as_uint(f);
  return (u & 0x80000000u) ? ~u : (u | 0x80000000u);
}
__device__ __forceinline__ float fdec(unsigned u){
  return __uint_as_float((u & 0x80000000u) ? (u & 0x7fffffffu) : ~u);
}

// Fused dual GEMM: xl = x@Wl + bl, xr = x@Wr + br.  Block = 256 thr,
// 32 nodes/block; threads 0..127 -> Wl, 128..255 -> Wr, d = tid&127.
__global__ __launch_bounds__(256) void gemm_dual(
    const float* __restrict__ x,
    const float* __restrict__ Wl, const float* __restrict__ bl,
    const float* __restrict__ Wr, const float* __restrict__ br,
    float* __restrict__ xl, float* __restrict__ xr)
{
  __shared__ float xs[32*DIM];
  int n0 = blockIdx.x * 32;
  for (int t = threadIdx.x; t < 32*DIM; t += 256) {
    int i = t >> 7, k = t & 127;
    int n = n0 + i;
    xs[t] = (n < N_NODES) ? x[(size_t)n*DIM + k] : 0.f;
  }
  __syncthreads();
  int d = threadIdx.x & 127;
  int half = threadIdx.x >> 7;
  const float* W = half ? Wr : Wl;
  const float* B = half ? br : bl;
  float acc[32];
  #pragma unroll
  for (int i = 0; i < 32; i++) acc[i] = 0.f;
  for (int k4 = 0; k4 < 32; k4++) {
    float w0 = W[(k4*4+0)*DIM + d];
    float w1 = W[(k4*4+1)*DIM + d];
    float w2 = W[(k4*4+2)*DIM + d];
    float w3 = W[(k4*4+3)*DIM + d];
    #pragma unroll
    for (int i = 0; i < 32; i++) {
      float4 xv = *(const float4*)(&xs[i*DIM + k4*4]);
      acc[i] = fmaf(xv.x, w0, acc[i]);
      acc[i] = fmaf(xv.y, w1, acc[i]);
      acc[i] = fmaf(xv.z, w2, acc[i]);
      acc[i] = fmaf(xv.w, w3, acc[i]);
    }
  }
  float bv = B[d];
  float* outp = half ? xr : xl;
  for (int i = 0; i < 32; i++) {
    int n = n0 + i;
    if (n < N_NODES) outp[(size_t)n*DIM + d] = acc[i] + bv;
  }
}

// One wave (64 lanes) per edge: logit = att . leakyrelu(xl[src] + xr[dst]);
// segment-max into menc[dst] via encoded atomicMax.
__global__ __launch_bounds__(256) void edge_logits(
    const float* __restrict__ xl, const float* __restrict__ xr,
    const int* __restrict__ src, const int* __restrict__ dst,
    const float* __restrict__ att,
    float* __restrict__ logit, unsigned* __restrict__ menc)
{
  int e = (blockIdx.x * 256 + threadIdx.x) >> 6;
  int lane = threadIdx.x & 63;
  if (e >= N_EDGES) return;
  int si = src[e], di = dst[e];
  float2 a = *(const float2*)(xl + (size_t)si*DIM + lane*2);
  float2 b = *(const float2*)(xr + (size_t)di*DIM + lane*2);
  float s0 = a.x + b.x, s1 = a.y + b.y;
  s0 = s0 > 0.f ? s0 : 0.2f*s0;
  s1 = s1 > 0.f ? s1 : 0.2f*s1;
  float p = att[lane*2] * s0 + att[lane*2+1] * s1;
  #pragma unroll
  for (int o = 32; o > 0; o >>= 1) p += __shfl_xor(p, o, 64);
  if (lane == 0) {
    logit[e] = p;
    atomicMax(menc + di, fenc(p));
  }
}

// One wave per edge: w = exp(logit - m[dst]); accumulate denominator s[dst]
// and unnormalized numerator out_un[dst,:] += w * xl[src,:].
__global__ __launch_bounds__(256) void edge_acc(
    const float* __restrict__ xl,
    const int* __restrict__ src, const int* __restrict__ dst,
    const float* __restrict__ logit, const unsigned* __restrict__ menc,
    float* __restrict__ s, float* __restrict__ out_un)
{
  int e = (blockIdx.x * 256 + threadIdx.x) >> 6;
  int lane = threadIdx.x & 63;
  if (e >= N_EDGES) return;
  int si = src[e], di = dst[e];
  float w = __expf(logit[e] - fdec(menc[di]));
  if (lane == 0) unsafeAtomicAdd(s + di, w);
  float2 v = *(const float2*)(xl + (size_t)si*DIM + lane*2);
  unsafeAtomicAdd(out_un + (size_t)di*DIM + lane*2,     w * v.x);
  unsafeAtomicAdd(out_un + (size_t)di*DIM + lane*2 + 1, w * v.y);
}

// out = relu(out_un / max(s,1e-16) + bias)
__global__ __launch_bounds__(256) void finalize_k(
    const float* __restrict__ out_un, const float* __restrict__ s,
    const float* __restrict__ bias, float* __restrict__ out)
{
  int idx = blockIdx.x * 256 + threadIdx.x;
  if (idx >= N_NODES*DIM) return;
  int n = idx >> 7, d = idx & 127;
  float denom = fmaxf(s[n], 1e-16f);
  float v = out_un[idx] / denom + bias[d];
  out[idx] = fmaxf(v, 0.f);
}

extern "C" void kernel_launch(void* const* d_in, const int* in_sizes, int n_in,
                              void* d_out, int out_size, void* d_ws, size_t ws_size,
                              hipStream_t stream)
{
  const float* node_fts = (const float*)d_in[0];
  const int*  edge_index = (const int*)d_in[1];
  const float* Wl1 = (const float*)d_in[2];
  const float* bl1 = (const float*)d_in[3];
  const float* Wr1 = (const float*)d_in[4];
  const float* br1 = (const float*)d_in[5];
  const float* att1 = (const float*)d_in[6];
  const float* bias1 = (const float*)d_in[7];
  const float* Wl2 = (const float*)d_in[8];
  const float* bl2 = (const float*)d_in[9];
  const float* Wr2 = (const float*)d_in[10];
  const float* br2 = (const float*)d_in[11];
  const float* att2 = (const float*)d_in[12];
  const float* bias2 = (const float*)d_in[13];
  const int* src = edge_index;
  const int* dst = edge_index + N_EDGES;

  float* xl = (float*)d_ws;
  float* xr = xl + (size_t)N_NODES*DIM;
  float* h  = xr + (size_t)N_NODES*DIM;
  float* out_un = h + (size_t)N_NODES*DIM;
  float* s = out_un + (size_t)N_NODES*DIM;
  unsigned* menc = (unsigned*)(s + N_NODES);
  float* logit = (float*)(menc + N_NODES);

  size_t zero_bytes = ((size_t)N_NODES*DIM + 2*(size_t)N_NODES) * 4;

  int gemm_blocks = (N_NODES + 31)/32;
  int edge_blocks = (N_EDGES*64 + 255)/256;
  int fin_blocks  = (N_NODES*DIM + 255)/256;

  // ---- layer 1 ----
  hipMemsetAsync(out_un, 0, zero_bytes, stream);
  gemm_dual<<<gemm_blocks, 256, 0, stream>>>(node_fts, Wl1, bl1, Wr1, br1, xl, xr);
  edge_logits<<<edge_blocks, 256, 0, stream>>>(xl, xr, src, dst, att1, logit, menc);
  edge_acc<<<edge_blocks, 256, 0, stream>>>(xl, src, dst, logit, menc, s, out_un);
  finalize_k<<<fin_blocks, 256, 0, stream>>>(out_un, s, bias1, h);

  // ---- layer 2 ----
  hipMemsetAsync(out_un, 0, zero_bytes, stream);
  gemm_dual<<<gemm_blocks, 256, 0, stream>>>(h, Wl2, bl2, Wr2, br2, xl, xr);
  edge_logits<<<edge_blocks, 256, 0, stream>>>(xl, xr, src, dst, att2, logit, menc);
  edge_acc<<<edge_blocks, 256, 0, stream>>>(xl, src, dst, logit, menc, s, out_un);
  finalize_k<<<fin_blocks, 256, 0, stream>>>(out_un, s, bias2, (float*)d_out);
}

// Round 3
// 687.074 us; speedup vs baseline: 2.9158x; 2.9158x over previous
//
#include <hip/hip_runtime.h>
#include <hip/hip_bf16.h>

#define N_NODES 50000
#define N_EDGES 800000
#define DIM 128

// ---------------- CSR build (per launch; graph-capture safe) ----------------

__global__ __launch_bounds__(256) void hist_k(
    const int* __restrict__ dst, int* __restrict__ deg)
{
  int e = blockIdx.x * 256 + threadIdx.x;
  if (e < N_EDGES) atomicAdd(deg + dst[e], 1);
}

// single-block exclusive scan over deg[0..N); writes row_start and cursor
__global__ __launch_bounds__(1024) void scan_k(
    const int* __restrict__ deg, int* __restrict__ row_start,
    int* __restrict__ cursor)
{
  __shared__ int partial[1024];
  const int C = (N_NODES + 1023) / 1024;   // 49
  int t = threadIdx.x;
  int base = t * C;
  int sum = 0;
  for (int i = 0; i < C; i++) {
    int idx = base + i;
    if (idx < N_NODES) sum += deg[idx];
  }
  partial[t] = sum;
  __syncthreads();
  for (int off = 1; off < 1024; off <<= 1) {
    int add = (t >= off) ? partial[t - off] : 0;
    __syncthreads();
    partial[t] += add;
    __syncthreads();
  }
  int run = partial[t] - sum;   // exclusive prefix of this thread's chunk
  for (int i = 0; i < C; i++) {
    int idx = base + i;
    if (idx < N_NODES) {
      row_start[idx] = run;
      cursor[idx] = run;
      run += deg[idx];
    }
  }
  if (t == 0) row_start[N_NODES] = N_EDGES;
}

__global__ __launch_bounds__(256) void scatter_k(
    const int* __restrict__ src, const int* __restrict__ dst,
    int* __restrict__ cursor, int* __restrict__ csr_src)
{
  int e = blockIdx.x * 256 + threadIdx.x;
  if (e >= N_EDGES) return;
  int pos = atomicAdd(cursor + dst[e], 1);
  csr_src[pos] = src[e];
}

// ---------------- dense phase ----------------

// Fused dual GEMM: xl = x@Wl + bl, xr = x@Wr + br.  Block = 256 thr,
// 32 nodes/block; threads 0..127 -> Wl, 128..255 -> Wr, d = tid&127.
__global__ __launch_bounds__(256) void gemm_dual(
    const float* __restrict__ x,
    const float* __restrict__ Wl, const float* __restrict__ bl,
    const float* __restrict__ Wr, const float* __restrict__ br,
    float* __restrict__ xl, float* __restrict__ xr)
{
  __shared__ float xs[32*DIM];
  int n0 = blockIdx.x * 32;
  for (int t = threadIdx.x; t < 32*DIM; t += 256) {
    int i = t >> 7, k = t & 127;
    int n = n0 + i;
    xs[t] = (n < N_NODES) ? x[(size_t)n*DIM + k] : 0.f;
  }
  __syncthreads();
  int d = threadIdx.x & 127;
  int half = threadIdx.x >> 7;
  const float* W = half ? Wr : Wl;
  const float* B = half ? br : bl;
  float acc[32];
  #pragma unroll
  for (int i = 0; i < 32; i++) acc[i] = 0.f;
  for (int k4 = 0; k4 < 32; k4++) {
    float w0 = W[(k4*4+0)*DIM + d];
    float w1 = W[(k4*4+1)*DIM + d];
    float w2 = W[(k4*4+2)*DIM + d];
    float w3 = W[(k4*4+3)*DIM + d];
    #pragma unroll
    for (int i = 0; i < 32; i++) {
      float4 xv = *(const float4*)(&xs[i*DIM + k4*4]);
      acc[i] = fmaf(xv.x, w0, acc[i]);
      acc[i] = fmaf(xv.y, w1, acc[i]);
      acc[i] = fmaf(xv.z, w2, acc[i]);
      acc[i] = fmaf(xv.w, w3, acc[i]);
    }
  }
  float bv = B[d];
  float* outp = half ? xr : xl;
  for (int i = 0; i < 32; i++) {
    int n = n0 + i;
    if (n < N_NODES) outp[(size_t)n*DIM + d] = acc[i] + bv;
  }
}

// ---------------- fused edge phase: one wave per node, online softmax ------
// lane owns dims {2*lane, 2*lane+1}. Per incoming edge: gather xl[src] row,
// logit = att . leakyrelu(xl[src]+xr[node]) via wave shuffle-reduce, then
// flash-style (m,l,acc) update. Epilogue: relu(acc/max(l,eps) + bias).
__global__ __launch_bounds__(256) void gat_gather(
    const float* __restrict__ xl, const float* __restrict__ xr,
    const int* __restrict__ row_start, const int* __restrict__ csr_src,
    const float* __restrict__ att, const float* __restrict__ bias,
    float* __restrict__ out)
{
  int node = (blockIdx.x * 256 + threadIdx.x) >> 6;
  int lane = threadIdx.x & 63;
  if (node >= N_NODES) return;
  int r0 = row_start[node], r1 = row_start[node + 1];
  float2 xrv = *(const float2*)(xr + (size_t)node*DIM + lane*2);
  float a0 = att[lane*2], a1 = att[lane*2+1];
  float m = -INFINITY, l = 0.f, acc0 = 0.f, acc1 = 0.f;
  for (int r = r0; r < r1; r++) {
    int si = csr_src[r];
    float2 v = *(const float2*)(xl + (size_t)si*DIM + lane*2);
    float s0 = v.x + xrv.x, s1 = v.y + xrv.y;
    s0 = s0 > 0.f ? s0 : 0.2f*s0;
    s1 = s1 > 0.f ? s1 : 0.2f*s1;
    float p = a0*s0 + a1*s1;
    #pragma unroll
    for (int o = 32; o > 0; o >>= 1) p += __shfl_xor(p, o, 64);
    float mn = fmaxf(m, p);
    float scale = __expf(m - mn);   // first iter: exp(-inf) = 0
    float w = __expf(p - mn);
    l = fmaf(l, scale, w);
    acc0 = fmaf(acc0, scale, w * v.x);
    acc1 = fmaf(acc1, scale, w * v.y);
    m = mn;
  }
  float denom = fmaxf(l, 1e-16f);
  float2 ov;
  ov.x = fmaxf(acc0 / denom + bias[lane*2],     0.f);
  ov.y = fmaxf(acc1 / denom + bias[lane*2 + 1], 0.f);
  *(float2*)(out + (size_t)node*DIM + lane*2) = ov;
}

extern "C" void kernel_launch(void* const* d_in, const int* in_sizes, int n_in,
                              void* d_out, int out_size, void* d_ws, size_t ws_size,
                              hipStream_t stream)
{
  const float* node_fts = (const float*)d_in[0];
  const int*  edge_index = (const int*)d_in[1];
  const float* Wl1 = (const float*)d_in[2];
  const float* bl1 = (const float*)d_in[3];
  const float* Wr1 = (const float*)d_in[4];
  const float* br1 = (const float*)d_in[5];
  const float* att1 = (const float*)d_in[6];
  const float* bias1 = (const float*)d_in[7];
  const float* Wl2 = (const float*)d_in[8];
  const float* bl2 = (const float*)d_in[9];
  const float* Wr2 = (const float*)d_in[10];
  const float* br2 = (const float*)d_in[11];
  const float* att2 = (const float*)d_in[12];
  const float* bias2 = (const float*)d_in[13];
  const int* src = edge_index;
  const int* dst = edge_index + N_EDGES;

  float* xl = (float*)d_ws;                       // N*D
  float* xr = xl + (size_t)N_NODES*DIM;           // N*D
  float* h  = xr + (size_t)N_NODES*DIM;           // N*D
  int* deg       = (int*)(h + (size_t)N_NODES*DIM);
  int* row_start = deg + N_NODES;                 // N+1
  int* cursor    = row_start + N_NODES + 1;       // N
  int* csr_src   = cursor + N_NODES;              // E

  int eb = (N_EDGES + 255) / 256;
  int gemm_blocks = (N_NODES + 31) / 32;
  int node_blocks = (N_NODES + 3) / 4;            // 4 waves/block, wave/node

  // ---- CSR build (edge_index is identical for both layers) ----
  hipMemsetAsync(deg, 0, N_NODES * sizeof(int), stream);
  hist_k<<<eb, 256, 0, stream>>>(dst, deg);
  scan_k<<<1, 1024, 0, stream>>>(deg, row_start, cursor);
  scatter_k<<<eb, 256, 0, stream>>>(src, dst, cursor, csr_src);

  // ---- layer 1 ----
  gemm_dual<<<gemm_blocks, 256, 0, stream>>>(node_fts, Wl1, bl1, Wr1, br1, xl, xr);
  gat_gather<<<node_blocks, 256, 0, stream>>>(xl, xr, row_start, csr_src, att1, bias1, h);

  // ---- layer 2 ----
  gemm_dual<<<gemm_blocks, 256, 0, stream>>>(h, Wl2, bl2, Wr2, br2, xl, xr);
  gat_gather<<<node_blocks, 256, 0, stream>>>(xl, xr, row_start, csr_src, att2, bias2, (float*)d_out);
}

// Round 4
// 569.980 us; speedup vs baseline: 3.5149x; 1.2054x over previous
//
#include <hip/hip_runtime.h>
#include <hip/hip_bf16.h>

#define N_NODES 50000
#define N_EDGES 800000
#define DIM 128
#define SCAN_BLOCKS ((N_NODES + 255) / 256)   // 196

// ---------------- CSR build (per launch; graph-capture safe) ----------------

__global__ __launch_bounds__(256) void hist_k(
    const int* __restrict__ dst, int* __restrict__ deg)
{
  int e = blockIdx.x * 256 + threadIdx.x;
  if (e < N_EDGES) atomicAdd(deg + dst[e], 1);
}

// level-1: per-block exclusive scan of 256 degrees; emit block total
__global__ __launch_bounds__(256) void scan_part_k(
    const int* __restrict__ deg, int* __restrict__ excl,
    int* __restrict__ blocksum)
{
  int t = threadIdx.x, lane = t & 63, w = t >> 6;
  int idx = blockIdx.x * 256 + t;
  int v = (idx < N_NODES) ? deg[idx] : 0;
  int inc = v;
  #pragma unroll
  for (int off = 1; off < 64; off <<= 1) {
    int y = __shfl_up(inc, off, 64);
    if (lane >= off) inc += y;
  }
  __shared__ int wsum[4];
  if (lane == 63) wsum[w] = inc;
  __syncthreads();
  int wpre = 0;
  #pragma unroll
  for (int i = 0; i < 4; i++) if (i < w) wpre += wsum[i];
  if (idx < N_NODES) excl[idx] = wpre + inc - v;
  if (t == 255) blocksum[blockIdx.x] = wpre + inc;
}

// level-2: single small block scans the 196 block totals (exclusive)
__global__ __launch_bounds__(256) void scan_tops_k(
    const int* __restrict__ blocksum, int* __restrict__ tops)
{
  int t = threadIdx.x, lane = t & 63, w = t >> 6;
  int v = (t < SCAN_BLOCKS) ? blocksum[t] : 0;
  int inc = v;
  #pragma unroll
  for (int off = 1; off < 64; off <<= 1) {
    int y = __shfl_up(inc, off, 64);
    if (lane >= off) inc += y;
  }
  __shared__ int wsum[4];
  if (lane == 63) wsum[w] = inc;
  __syncthreads();
  int wpre = 0;
  #pragma unroll
  for (int i = 0; i < 4; i++) if (i < w) wpre += wsum[i];
  if (t < SCAN_BLOCKS) tops[t] = wpre + inc - v;
}

// level-3: add block offsets, write row_start and cursor
__global__ __launch_bounds__(256) void scan_add_k(
    const int* __restrict__ excl, const int* __restrict__ tops,
    int* __restrict__ row_start, int* __restrict__ cursor)
{
  int idx = blockIdx.x * 256 + threadIdx.x;
  if (idx < N_NODES) {
    int r = excl[idx] + tops[blockIdx.x];
    row_start[idx] = r;
    cursor[idx] = r;
  }
  if (idx == 0) row_start[N_NODES] = N_EDGES;
}

__global__ __launch_bounds__(256) void scatter_k(
    const int* __restrict__ src, const int* __restrict__ dst,
    int* __restrict__ cursor, int* __restrict__ csr_src)
{
  int e = blockIdx.x * 256 + threadIdx.x;
  if (e >= N_EDGES) return;
  int pos = atomicAdd(cursor + dst[e], 1);
  csr_src[pos] = src[e];
}

// ---------------- dense phase ----------------

// Fused dual GEMM: xl = x@Wl + bl, xr = x@Wr + br.  Block = 256 thr,
// 32 nodes/block; threads 0..127 -> Wl, 128..255 -> Wr, d = tid&127.
__global__ __launch_bounds__(256) void gemm_dual(
    const float* __restrict__ x,
    const float* __restrict__ Wl, const float* __restrict__ bl,
    const float* __restrict__ Wr, const float* __restrict__ br,
    float* __restrict__ xl, float* __restrict__ xr)
{
  __shared__ float xs[32*DIM];
  int n0 = blockIdx.x * 32;
  for (int t = threadIdx.x; t < 32*DIM; t += 256) {
    int i = t >> 7, k = t & 127;
    int n = n0 + i;
    xs[t] = (n < N_NODES) ? x[(size_t)n*DIM + k] : 0.f;
  }
  __syncthreads();
  int d = threadIdx.x & 127;
  int half = threadIdx.x >> 7;
  const float* W = half ? Wr : Wl;
  const float* B = half ? br : bl;
  float acc[32];
  #pragma unroll
  for (int i = 0; i < 32; i++) acc[i] = 0.f;
  for (int k4 = 0; k4 < 32; k4++) {
    float w0 = W[(k4*4+0)*DIM + d];
    float w1 = W[(k4*4+1)*DIM + d];
    float w2 = W[(k4*4+2)*DIM + d];
    float w3 = W[(k4*4+3)*DIM + d];
    #pragma unroll
    for (int i = 0; i < 32; i++) {
      float4 xv = *(const float4*)(&xs[i*DIM + k4*4]);
      acc[i] = fmaf(xv.x, w0, acc[i]);
      acc[i] = fmaf(xv.y, w1, acc[i]);
      acc[i] = fmaf(xv.z, w2, acc[i]);
      acc[i] = fmaf(xv.w, w3, acc[i]);
    }
  }
  float bv = B[d];
  float* outp = half ? xr : xl;
  for (int i = 0; i < 32; i++) {
    int n = n0 + i;
    if (n < N_NODES) outp[(size_t)n*DIM + d] = acc[i] + bv;
  }
}

// ---------------- fused edge phase: one wave per node, online softmax ------
__global__ __launch_bounds__(256) void gat_gather(
    const float* __restrict__ xl, const float* __restrict__ xr,
    const int* __restrict__ row_start, const int* __restrict__ csr_src,
    const float* __restrict__ att, const float* __restrict__ bias,
    float* __restrict__ out)
{
  int node = (blockIdx.x * 256 + threadIdx.x) >> 6;
  int lane = threadIdx.x & 63;
  if (node >= N_NODES) return;
  int r0 = row_start[node], r1 = row_start[node + 1];
  float2 xrv = *(const float2*)(xr + (size_t)node*DIM + lane*2);
  float a0 = att[lane*2], a1 = att[lane*2+1];
  float m = -INFINITY, l = 0.f, acc0 = 0.f, acc1 = 0.f;
  for (int r = r0; r < r1; r++) {
    int si = csr_src[r];
    float2 v = *(const float2*)(xl + (size_t)si*DIM + lane*2);
    float s0 = v.x + xrv.x, s1 = v.y + xrv.y;
    s0 = s0 > 0.f ? s0 : 0.2f*s0;
    s1 = s1 > 0.f ? s1 : 0.2f*s1;
    float p = a0*s0 + a1*s1;
    #pragma unroll
    for (int o = 32; o > 0; o >>= 1) p += __shfl_xor(p, o, 64);
    float mn = fmaxf(m, p);
    float scale = __expf(m - mn);   // first iter: exp(-inf) = 0
    float w = __expf(p - mn);
    l = fmaf(l, scale, w);
    acc0 = fmaf(acc0, scale, w * v.x);
    acc1 = fmaf(acc1, scale, w * v.y);
    m = mn;
  }
  float denom = fmaxf(l, 1e-16f);
  float2 ov;
  ov.x = fmaxf(acc0 / denom + bias[lane*2],     0.f);
  ov.y = fmaxf(acc1 / denom + bias[lane*2 + 1], 0.f);
  *(float2*)(out + (size_t)node*DIM + lane*2) = ov;
}

extern "C" void kernel_launch(void* const* d_in, const int* in_sizes, int n_in,
                              void* d_out, int out_size, void* d_ws, size_t ws_size,
                              hipStream_t stream)
{
  const float* node_fts = (const float*)d_in[0];
  const int*  edge_index = (const int*)d_in[1];
  const float* Wl1 = (const float*)d_in[2];
  const float* bl1 = (const float*)d_in[3];
  const float* Wr1 = (const float*)d_in[4];
  const float* br1 = (const float*)d_in[5];
  const float* att1 = (const float*)d_in[6];
  const float* bias1 = (const float*)d_in[7];
  const float* Wl2 = (const float*)d_in[8];
  const float* bl2 = (const float*)d_in[9];
  const float* Wr2 = (const float*)d_in[10];
  const float* br2 = (const float*)d_in[11];
  const float* att2 = (const float*)d_in[12];
  const float* bias2 = (const float*)d_in[13];
  const int* src = edge_index;
  const int* dst = edge_index + N_EDGES;

  float* xl = (float*)d_ws;                       // N*D
  float* xr = xl + (size_t)N_NODES*DIM;           // N*D
  float* h  = xr + (size_t)N_NODES*DIM;           // N*D
  int* deg       = (int*)(h + (size_t)N_NODES*DIM);
  int* row_start = deg + N_NODES;                 // N+1
  int* cursor    = row_start + N_NODES + 1;       // N
  int* csr_src   = cursor + N_NODES;              // E
  int* excl      = csr_src + N_EDGES;             // N
  int* blocksum  = excl + N_NODES;                // SCAN_BLOCKS
  int* tops      = blocksum + SCAN_BLOCKS;        // SCAN_BLOCKS

  int eb = (N_EDGES + 255) / 256;
  int gemm_blocks = (N_NODES + 31) / 32;
  int node_blocks = (N_NODES + 3) / 4;            // 4 waves/block, wave/node

  // ---- CSR build (edge_index is identical for both layers) ----
  hipMemsetAsync(deg, 0, N_NODES * sizeof(int), stream);
  hist_k<<<eb, 256, 0, stream>>>(dst, deg);
  scan_part_k<<<SCAN_BLOCKS, 256, 0, stream>>>(deg, excl, blocksum);
  scan_tops_k<<<1, 256, 0, stream>>>(blocksum, tops);
  scan_add_k<<<SCAN_BLOCKS, 256, 0, stream>>>(excl, tops, row_start, cursor);
  scatter_k<<<eb, 256, 0, stream>>>(src, dst, cursor, csr_src);

  // ---- layer 1 ----
  gemm_dual<<<gemm_blocks, 256, 0, stream>>>(node_fts, Wl1, bl1, Wr1, br1, xl, xr);
  gat_gather<<<node_blocks, 256, 0, stream>>>(xl, xr, row_start, csr_src, att1, bias1, h);

  // ---- layer 2 ----
  gemm_dual<<<gemm_blocks, 256, 0, stream>>>(h, Wl2, bl2, Wr2, br2, xl, xr);
  gat_gather<<<node_blocks, 256, 0, stream>>>(xl, xr, row_start, csr_src, att2, bias2, (float*)d_out);
}

// Round 5
// 424.965 us; speedup vs baseline: 4.7143x; 1.3412x over previous
//
#include <hip/hip_runtime.h>
#include <hip/hip_bf16.h>

#define N_NODES 50000
#define N_EDGES 800000
#define DIM 128
#define SCAN_BLOCKS ((N_NODES + 255) / 256)   // 196
#define GN 64                                  // nodes per gemm block

// ---------------- CSR build (per launch; graph-capture safe) ----------------

__global__ __launch_bounds__(256) void hist_k(
    const int* __restrict__ dst, int* __restrict__ deg)
{
  int e = blockIdx.x * 256 + threadIdx.x;
  if (e < N_EDGES) atomicAdd(deg + dst[e], 1);
}

// level-1: per-block exclusive scan of 256 degrees; emit block total
__global__ __launch_bounds__(256) void scan_part_k(
    const int* __restrict__ deg, int* __restrict__ excl,
    int* __restrict__ blocksum)
{
  int t = threadIdx.x, lane = t & 63, w = t >> 6;
  int idx = blockIdx.x * 256 + t;
  int v = (idx < N_NODES) ? deg[idx] : 0;
  int inc = v;
  #pragma unroll
  for (int off = 1; off < 64; off <<= 1) {
    int y = __shfl_up(inc, off, 64);
    if (lane >= off) inc += y;
  }
  __shared__ int wsum[4];
  if (lane == 63) wsum[w] = inc;
  __syncthreads();
  int wpre = 0;
  #pragma unroll
  for (int i = 0; i < 4; i++) if (i < w) wpre += wsum[i];
  if (idx < N_NODES) excl[idx] = wpre + inc - v;
  if (t == 255) blocksum[blockIdx.x] = wpre + inc;
}

// level-2: single small block scans the 196 block totals (exclusive)
__global__ __launch_bounds__(256) void scan_tops_k(
    const int* __restrict__ blocksum, int* __restrict__ tops)
{
  int t = threadIdx.x, lane = t & 63, w = t >> 6;
  int v = (t < SCAN_BLOCKS) ? blocksum[t] : 0;
  int inc = v;
  #pragma unroll
  for (int off = 1; off < 64; off <<= 1) {
    int y = __shfl_up(inc, off, 64);
    if (lane >= off) inc += y;
  }
  __shared__ int wsum[4];
  if (lane == 63) wsum[w] = inc;
  __syncthreads();
  int wpre = 0;
  #pragma unroll
  for (int i = 0; i < 4; i++) if (i < w) wpre += wsum[i];
  if (t < SCAN_BLOCKS) tops[t] = wpre + inc - v;
}

// level-3: add block offsets, write row_start and cursor
__global__ __launch_bounds__(256) void scan_add_k(
    const int* __restrict__ excl, const int* __restrict__ tops,
    int* __restrict__ row_start, int* __restrict__ cursor)
{
  int idx = blockIdx.x * 256 + threadIdx.x;
  if (idx < N_NODES) {
    int r = excl[idx] + tops[blockIdx.x];
    row_start[idx] = r;
    cursor[idx] = r;
  }
  if (idx == 0) row_start[N_NODES] = N_EDGES;
}

__global__ __launch_bounds__(256) void scatter_k(
    const int* __restrict__ src, const int* __restrict__ dst,
    int* __restrict__ cursor, int* __restrict__ csr_src)
{
  int e = blockIdx.x * 256 + threadIdx.x;
  if (e >= N_EDGES) return;
  int pos = atomicAdd(cursor + dst[e], 1);
  csr_src[pos] = src[e];
}

// ---------------- dense phase ----------------
// Dual GEMM, register-tiled: block = 64 nodes, 256 threads as 4 rows x 64
// cols. Thread (row,col): 16 nodes (row*16..+15) x 4 dims. col<32 -> Wl dims
// 4c..4c+3, col>=32 -> Wr. Per k4: x float4 reused over 4 dims, W float4
// reused over 16 nodes -> 256 FMA : 16 ds_read_b128 : 4 global float4.
__global__ __launch_bounds__(256) void gemm_dual(
    const float* __restrict__ x,
    const float* __restrict__ Wl, const float* __restrict__ bl,
    const float* __restrict__ Wr, const float* __restrict__ br,
    float* __restrict__ xl, float* __restrict__ xr)
{
  __shared__ float xs[GN*DIM];  // 32 KB
  int n0 = blockIdx.x * GN;
  for (int t = threadIdx.x; t < GN*DIM/4; t += 256) {
    int i = t >> 5, k4 = t & 31;
    int n = n0 + i;
    float4 val = make_float4(0.f, 0.f, 0.f, 0.f);
    if (n < N_NODES) val = *(const float4*)(x + (size_t)n*DIM + k4*4);
    *(float4*)(xs + i*DIM + k4*4) = val;
  }
  __syncthreads();

  int row = threadIdx.x >> 6;          // 0..3
  int col = threadIdx.x & 63;          // 0..63
  int half = col >> 5;
  int d = (col & 31) * 4;
  const float* __restrict__ W = half ? Wr : Wl;
  const float* __restrict__ B = half ? br : bl;
  int ibase = row * 16;

  float acc[16][4];
  #pragma unroll
  for (int i = 0; i < 16; i++)
    #pragma unroll
    for (int c = 0; c < 4; c++) acc[i][c] = 0.f;

  for (int k4 = 0; k4 < 32; k4++) {
    float4 w0 = *(const float4*)(W + (size_t)(k4*4+0)*DIM + d);
    float4 w1 = *(const float4*)(W + (size_t)(k4*4+1)*DIM + d);
    float4 w2 = *(const float4*)(W + (size_t)(k4*4+2)*DIM + d);
    float4 w3 = *(const float4*)(W + (size_t)(k4*4+3)*DIM + d);
    #pragma unroll
    for (int i = 0; i < 16; i++) {
      float4 xv = *(const float4*)(&xs[(ibase + i)*DIM + k4*4]);
      acc[i][0] = fmaf(xv.x, w0.x, acc[i][0]);
      acc[i][1] = fmaf(xv.x, w0.y, acc[i][1]);
      acc[i][2] = fmaf(xv.x, w0.z, acc[i][2]);
      acc[i][3] = fmaf(xv.x, w0.w, acc[i][3]);
      acc[i][0] = fmaf(xv.y, w1.x, acc[i][0]);
      acc[i][1] = fmaf(xv.y, w1.y, acc[i][1]);
      acc[i][2] = fmaf(xv.y, w1.z, acc[i][2]);
      acc[i][3] = fmaf(xv.y, w1.w, acc[i][3]);
      acc[i][0] = fmaf(xv.z, w2.x, acc[i][0]);
      acc[i][1] = fmaf(xv.z, w2.y, acc[i][1]);
      acc[i][2] = fmaf(xv.z, w2.z, acc[i][2]);
      acc[i][3] = fmaf(xv.z, w2.w, acc[i][3]);
      acc[i][0] = fmaf(xv.w, w3.x, acc[i][0]);
      acc[i][1] = fmaf(xv.w, w3.y, acc[i][1]);
      acc[i][2] = fmaf(xv.w, w3.z, acc[i][2]);
      acc[i][3] = fmaf(xv.w, w3.w, acc[i][3]);
    }
  }

  float4 bv = *(const float4*)(B + d);
  float* __restrict__ outp = half ? xr : xl;
  #pragma unroll
  for (int i = 0; i < 16; i++) {
    int n = n0 + ibase + i;
    if (n < N_NODES) {
      float4 o = make_float4(acc[i][0] + bv.x, acc[i][1] + bv.y,
                             acc[i][2] + bv.z, acc[i][3] + bv.w);
      *(float4*)(outp + (size_t)n*DIM + d) = o;
    }
  }
}

// ---------------- fused edge phase: one wave per node, online softmax ------
// 8-edge batches: 8 independent row gathers + 8 interleaved shuffle-reduce
// chains, then ONE rescale per batch. Tail: clamp index, mask p[j] = -inf
// (exp -> 0, exact zero contribution).
__global__ __launch_bounds__(256) void gat_gather(
    const float* __restrict__ xl, const float* __restrict__ xr,
    const int* __restrict__ row_start, const int* __restrict__ csr_src,
    const float* __restrict__ att, const float* __restrict__ bias,
    float* __restrict__ out)
{
  int node = (blockIdx.x * 256 + threadIdx.x) >> 6;
  int lane = threadIdx.x & 63;
  if (node >= N_NODES) return;
  int r0 = row_start[node], r1 = row_start[node + 1];
  float2 xrv = *(const float2*)(xr + (size_t)node*DIM + lane*2);
  float a0 = att[lane*2], a1 = att[lane*2+1];
  float m = -INFINITY, l = 0.f, acc0 = 0.f, acc1 = 0.f;
  int last = r1 - 1;
  for (int r = r0; r < r1; r += 8) {
    float2 v[8];
    float p[8];
    #pragma unroll
    for (int j = 0; j < 8; j++) {
      int rr = r + j;
      int rc = rr <= last ? rr : last;
      int si = csr_src[rc];
      v[j] = *(const float2*)(xl + (size_t)si*DIM + lane*2);
    }
    #pragma unroll
    for (int j = 0; j < 8; j++) {
      float s0 = v[j].x + xrv.x, s1 = v[j].y + xrv.y;
      s0 = s0 > 0.f ? s0 : 0.2f*s0;
      s1 = s1 > 0.f ? s1 : 0.2f*s1;
      p[j] = a0*s0 + a1*s1;
    }
    #pragma unroll
    for (int o = 32; o > 0; o >>= 1) {
      #pragma unroll
      for (int j = 0; j < 8; j++) p[j] += __shfl_xor(p[j], o, 64);
    }
    #pragma unroll
    for (int j = 0; j < 8; j++) if (r + j > last) p[j] = -INFINITY;
    float pmax = p[0];
    #pragma unroll
    for (int j = 1; j < 8; j++) pmax = fmaxf(pmax, p[j]);
    float mn = fmaxf(m, pmax);
    float scale = __expf(m - mn);   // first batch: exp(-inf) = 0
    l *= scale; acc0 *= scale; acc1 *= scale;
    #pragma unroll
    for (int j = 0; j < 8; j++) {
      float w = __expf(p[j] - mn);  // masked j: exp(-inf) = 0
      l += w;
      acc0 = fmaf(w, v[j].x, acc0);
      acc1 = fmaf(w, v[j].y, acc1);
    }
    m = mn;
  }
  float denom = fmaxf(l, 1e-16f);
  float2 ov;
  ov.x = fmaxf(acc0 / denom + bias[lane*2],     0.f);
  ov.y = fmaxf(acc1 / denom + bias[lane*2 + 1], 0.f);
  *(float2*)(out + (size_t)node*DIM + lane*2) = ov;
}

extern "C" void kernel_launch(void* const* d_in, const int* in_sizes, int n_in,
                              void* d_out, int out_size, void* d_ws, size_t ws_size,
                              hipStream_t stream)
{
  const float* node_fts = (const float*)d_in[0];
  const int*  edge_index = (const int*)d_in[1];
  const float* Wl1 = (const float*)d_in[2];
  const float* bl1 = (const float*)d_in[3];
  const float* Wr1 = (const float*)d_in[4];
  const float* br1 = (const float*)d_in[5];
  const float* att1 = (const float*)d_in[6];
  const float* bias1 = (const float*)d_in[7];
  const float* Wl2 = (const float*)d_in[8];
  const float* bl2 = (const float*)d_in[9];
  const float* Wr2 = (const float*)d_in[10];
  const float* br2 = (const float*)d_in[11];
  const float* att2 = (const float*)d_in[12];
  const float* bias2 = (const float*)d_in[13];
  const int* src = edge_index;
  const int* dst = edge_index + N_EDGES;

  float* xl = (float*)d_ws;                       // N*D
  float* xr = xl + (size_t)N_NODES*DIM;           // N*D
  float* h  = xr + (size_t)N_NODES*DIM;           // N*D
  int* deg       = (int*)(h + (size_t)N_NODES*DIM);
  int* row_start = deg + N_NODES;                 // N+1
  int* cursor    = row_start + N_NODES + 1;       // N
  int* csr_src   = cursor + N_NODES;              // E
  int* excl      = csr_src + N_EDGES;             // N
  int* blocksum  = excl + N_NODES;                // SCAN_BLOCKS
  int* tops      = blocksum + SCAN_BLOCKS;        // SCAN_BLOCKS

  int eb = (N_EDGES + 255) / 256;
  int gemm_blocks = (N_NODES + GN - 1) / GN;
  int node_blocks = (N_NODES + 3) / 4;            // 4 waves/block, wave/node

  // ---- CSR build (edge_index is identical for both layers) ----
  hipMemsetAsync(deg, 0, N_NODES * sizeof(int), stream);
  hist_k<<<eb, 256, 0, stream>>>(dst, deg);
  scan_part_k<<<SCAN_BLOCKS, 256, 0, stream>>>(deg, excl, blocksum);
  scan_tops_k<<<1, 256, 0, stream>>>(blocksum, tops);
  scan_add_k<<<SCAN_BLOCKS, 256, 0, stream>>>(excl, tops, row_start, cursor);
  scatter_k<<<eb, 256, 0, stream>>>(src, dst, cursor, csr_src);

  // ---- layer 1 ----
  gemm_dual<<<gemm_blocks, 256, 0, stream>>>(node_fts, Wl1, bl1, Wr1, br1, xl, xr);
  gat_gather<<<node_blocks, 256, 0, stream>>>(xl, xr, row_start, csr_src, att1, bias1, h);

  // ---- layer 2 ----
  gemm_dual<<<gemm_blocks, 256, 0, stream>>>(h, Wl2, bl2, Wr2, br2, xl, xr);
  gat_gather<<<node_blocks, 256, 0, stream>>>(xl, xr, row_start, csr_src, att2, bias2, (float*)d_out);
}

// Round 6
// 421.236 us; speedup vs baseline: 4.7560x; 1.0089x over previous
//
#include <hip/hip_runtime.h>
#include <hip/hip_bf16.h>

#define N_NODES 50000
#define N_EDGES 800000
#define DIM 128
#define SCAN_BLOCKS ((N_NODES + 255) / 256)   // 196
#define GBN 64                                 // nodes per gemm block

// ---------------- CSR build (per launch; graph-capture safe) ----------------

__global__ __launch_bounds__(256) void hist_k(
    const int* __restrict__ dst, int* __restrict__ deg)
{
  int e = blockIdx.x * 256 + threadIdx.x;
  if (e < N_EDGES) atomicAdd(deg + dst[e], 1);
}

__global__ __launch_bounds__(256) void scan_part_k(
    const int* __restrict__ deg, int* __restrict__ excl,
    int* __restrict__ blocksum)
{
  int t = threadIdx.x, lane = t & 63, w = t >> 6;
  int idx = blockIdx.x * 256 + t;
  int v = (idx < N_NODES) ? deg[idx] : 0;
  int inc = v;
  #pragma unroll
  for (int off = 1; off < 64; off <<= 1) {
    int y = __shfl_up(inc, off, 64);
    if (lane >= off) inc += y;
  }
  __shared__ int wsum[4];
  if (lane == 63) wsum[w] = inc;
  __syncthreads();
  int wpre = 0;
  #pragma unroll
  for (int i = 0; i < 4; i++) if (i < w) wpre += wsum[i];
  if (idx < N_NODES) excl[idx] = wpre + inc - v;
  if (t == 255) blocksum[blockIdx.x] = wpre + inc;
}

__global__ __launch_bounds__(256) void scan_tops_k(
    const int* __restrict__ blocksum, int* __restrict__ tops)
{
  int t = threadIdx.x, lane = t & 63, w = t >> 6;
  int v = (t < SCAN_BLOCKS) ? blocksum[t] : 0;
  int inc = v;
  #pragma unroll
  for (int off = 1; off < 64; off <<= 1) {
    int y = __shfl_up(inc, off, 64);
    if (lane >= off) inc += y;
  }
  __shared__ int wsum[4];
  if (lane == 63) wsum[w] = inc;
  __syncthreads();
  int wpre = 0;
  #pragma unroll
  for (int i = 0; i < 4; i++) if (i < w) wpre += wsum[i];
  if (t < SCAN_BLOCKS) tops[t] = wpre + inc - v;
}

__global__ __launch_bounds__(256) void scan_add_k(
    const int* __restrict__ excl, const int* __restrict__ tops,
    int* __restrict__ row_start, int* __restrict__ cursor)
{
  int idx = blockIdx.x * 256 + threadIdx.x;
  if (idx < N_NODES) {
    int r = excl[idx] + tops[blockIdx.x];
    row_start[idx] = r;
    cursor[idx] = r;
  }
  if (idx == 0) row_start[N_NODES] = N_EDGES;
}

__global__ __launch_bounds__(256) void scatter_k(
    const int* __restrict__ src, const int* __restrict__ dst,
    int* __restrict__ cursor, int* __restrict__ csr_src)
{
  int e = blockIdx.x * 256 + threadIdx.x;
  if (e >= N_EDGES) return;
  int pos = atomicAdd(cursor + dst[e], 1);
  csr_src[pos] = src[e];
}

// ---------------- dense phase ----------------
// Dual GEMM, lane = node: block = 64 nodes x 256 outdims (Wl 128 + Wr 128).
// Wave w handles 64 dims {w&1 half} of {w<2 ? Wl : Wr}; lane = node; per k:
// x from transposed LDS tile xs[k][node] (conflict-free b32), W row is
// wave-UNIFORM -> scalar loads (s_load), VALU does only v_fmac. acc[64]/lane.
__global__ __launch_bounds__(256) void gemm_dual(
    const float* __restrict__ x,
    const float* __restrict__ Wl, const float* __restrict__ bl,
    const float* __restrict__ Wr, const float* __restrict__ br,
    float* __restrict__ xl, float* __restrict__ xr)
{
  __shared__ float xs[DIM][GBN + 1];   // [k][node], padded: ~33 KB
  int tid = threadIdx.x;
  int n0 = blockIdx.x * GBN;
  for (int t = tid; t < GBN * 32; t += 256) {
    int i = t >> 5, k4 = t & 31;
    int n = n0 + i;
    float4 val = make_float4(0.f, 0.f, 0.f, 0.f);
    if (n < N_NODES) val = *(const float4*)(x + (size_t)n*DIM + k4*4);
    xs[k4*4+0][i] = val.x;
    xs[k4*4+1][i] = val.y;
    xs[k4*4+2][i] = val.z;
    xs[k4*4+3][i] = val.w;
  }
  __syncthreads();

  int wid = __builtin_amdgcn_readfirstlane(tid >> 6);  // 0..3, SGPR
  int lane = tid & 63;
  const float* __restrict__ W = (wid < 2) ? Wl : Wr;
  const float* __restrict__ B = (wid < 2) ? bl : br;
  float* __restrict__ outp    = (wid < 2) ? xl : xr;
  int dbase = (wid & 1) * 64;

  float acc[64];
  #pragma unroll
  for (int d = 0; d < 64; d++) acc[d] = 0.f;

  for (int k = 0; k < DIM; k++) {
    float xk = xs[k][lane];
    const float* __restrict__ wr = W + (size_t)k*DIM + dbase;  // uniform
    #pragma unroll
    for (int d = 0; d < 64; d++)
      acc[d] = fmaf(xk, wr[d], acc[d]);
  }

  int n = n0 + lane;
  if (n < N_NODES) {
    float* op = outp + (size_t)n*DIM + dbase;
    #pragma unroll
    for (int d4 = 0; d4 < 16; d4++) {
      float4 o;
      o.x = acc[d4*4+0] + B[dbase + d4*4+0];
      o.y = acc[d4*4+1] + B[dbase + d4*4+1];
      o.z = acc[d4*4+2] + B[dbase + d4*4+2];
      o.w = acc[d4*4+3] + B[dbase + d4*4+3];
      *(float4*)(op + d4*4) = o;
    }
  }
}

// ---------------- fused edge phase: 32 lanes/node, 2 nodes/wave ------------
// lane&31 owns 4 dims (float4). One gather instr fetches edge-rows for BOTH
// nodes; reduce = 5 shuffle steps within the 32-lane half; one online-softmax
// rescale per 8-edge batch. Masking by (t+j < deg) keeps empty nodes exact.
__global__ __launch_bounds__(256) void gat_gather(
    const float* __restrict__ xl, const float* __restrict__ xr,
    const int* __restrict__ row_start, const int* __restrict__ csr_src,
    const float* __restrict__ att, const float* __restrict__ bias,
    float* __restrict__ out)
{
  int wave = (blockIdx.x * 256 + threadIdx.x) >> 6;
  int lane = threadIdx.x & 63;
  int half = lane >> 5;
  int hl = lane & 31;
  int node = wave * 2 + half;
  bool valid = node < N_NODES;
  int nc = valid ? node : (N_NODES - 1);
  int r0 = row_start[nc], r1 = row_start[nc + 1];
  int deg = valid ? (r1 - r0) : 0;
  int last = r0 + deg - 1;
  int dmax = max(deg, __shfl_xor(deg, 32, 64));   // max over the 2 nodes

  float4 xrv = *(const float4*)(xr + (size_t)nc*DIM + hl*4);
  float4 av  = *(const float4*)(att + hl*4);
  float m = -INFINITY, l = 0.f;
  float4 acc = make_float4(0.f, 0.f, 0.f, 0.f);

  for (int t = 0; t < dmax; t += 8) {
    float4 v[8];
    float p[8];
    #pragma unroll
    for (int j = 0; j < 8; j++) {
      int rr = r0 + t + j;
      int rc = rr <= last ? rr : last;
      rc = rc >= 0 ? rc : 0;                       // deg==0 safety
      int si = csr_src[rc];
      v[j] = *(const float4*)(xl + (size_t)si*DIM + hl*4);
    }
    #pragma unroll
    for (int j = 0; j < 8; j++) {
      float s0 = v[j].x + xrv.x, s1 = v[j].y + xrv.y;
      float s2 = v[j].z + xrv.z, s3 = v[j].w + xrv.w;
      s0 = s0 > 0.f ? s0 : 0.2f*s0;
      s1 = s1 > 0.f ? s1 : 0.2f*s1;
      s2 = s2 > 0.f ? s2 : 0.2f*s2;
      s3 = s3 > 0.f ? s3 : 0.2f*s3;
      p[j] = av.x*s0 + av.y*s1 + av.z*s2 + av.w*s3;
    }
    #pragma unroll
    for (int o = 1; o <= 16; o <<= 1) {            // stays within 32-half
      #pragma unroll
      for (int j = 0; j < 8; j++) p[j] += __shfl_xor(p[j], o, 64);
    }
    #pragma unroll
    for (int j = 0; j < 8; j++) if (t + j >= deg) p[j] = -INFINITY;
    float pmax = p[0];
    #pragma unroll
    for (int j = 1; j < 8; j++) pmax = fmaxf(pmax, p[j]);
    float mn = fmaxf(m, pmax);
    float sc = (mn == -INFINITY) ? 0.f : __expf(m - mn);
    l *= sc; acc.x *= sc; acc.y *= sc; acc.z *= sc; acc.w *= sc;
    #pragma unroll
    for (int j = 0; j < 8; j++) {
      float w = (t + j < deg) ? __expf(p[j] - mn) : 0.f;
      l += w;
      acc.x = fmaf(w, v[j].x, acc.x);
      acc.y = fmaf(w, v[j].y, acc.y);
      acc.z = fmaf(w, v[j].z, acc.z);
      acc.w = fmaf(w, v[j].w, acc.w);
    }
    m = mn;
  }

  if (valid) {
    float denom = fmaxf(l, 1e-16f);
    float4 bv = *(const float4*)(bias + hl*4);
    float4 ov;
    ov.x = fmaxf(acc.x / denom + bv.x, 0.f);
    ov.y = fmaxf(acc.y / denom + bv.y, 0.f);
    ov.z = fmaxf(acc.z / denom + bv.z, 0.f);
    ov.w = fmaxf(acc.w / denom + bv.w, 0.f);
    *(float4*)(out + (size_t)node*DIM + hl*4) = ov;
  }
}

extern "C" void kernel_launch(void* const* d_in, const int* in_sizes, int n_in,
                              void* d_out, int out_size, void* d_ws, size_t ws_size,
                              hipStream_t stream)
{
  const float* node_fts = (const float*)d_in[0];
  const int*  edge_index = (const int*)d_in[1];
  const float* Wl1 = (const float*)d_in[2];
  const float* bl1 = (const float*)d_in[3];
  const float* Wr1 = (const float*)d_in[4];
  const float* br1 = (const float*)d_in[5];
  const float* att1 = (const float*)d_in[6];
  const float* bias1 = (const float*)d_in[7];
  const float* Wl2 = (const float*)d_in[8];
  const float* bl2 = (const float*)d_in[9];
  const float* Wr2 = (const float*)d_in[10];
  const float* br2 = (const float*)d_in[11];
  const float* att2 = (const float*)d_in[12];
  const float* bias2 = (const float*)d_in[13];
  const int* src = edge_index;
  const int* dst = edge_index + N_EDGES;

  float* xl = (float*)d_ws;                       // N*D
  float* xr = xl + (size_t)N_NODES*DIM;           // N*D
  float* h  = xr + (size_t)N_NODES*DIM;           // N*D
  int* deg       = (int*)(h + (size_t)N_NODES*DIM);
  int* row_start = deg + N_NODES;                 // N+1
  int* cursor    = row_start + N_NODES + 1;       // N
  int* csr_src   = cursor + N_NODES;              // E
  int* excl      = csr_src + N_EDGES;             // N
  int* blocksum  = excl + N_NODES;                // SCAN_BLOCKS
  int* tops      = blocksum + SCAN_BLOCKS;        // SCAN_BLOCKS

  int eb = (N_EDGES + 255) / 256;
  int gemm_blocks = (N_NODES + GBN - 1) / GBN;
  int gather_waves = (N_NODES + 1) / 2;
  int gather_blocks = (gather_waves + 3) / 4;     // 4 waves/block

  // ---- CSR build (edge_index is identical for both layers) ----
  hipMemsetAsync(deg, 0, N_NODES * sizeof(int), stream);
  hist_k<<<eb, 256, 0, stream>>>(dst, deg);
  scan_part_k<<<SCAN_BLOCKS, 256, 0, stream>>>(deg, excl, blocksum);
  scan_tops_k<<<1, 256, 0, stream>>>(blocksum, tops);
  scan_add_k<<<SCAN_BLOCKS, 256, 0, stream>>>(excl, tops, row_start, cursor);
  scatter_k<<<eb, 256, 0, stream>>>(src, dst, cursor, csr_src);

  // ---- layer 1 ----
  gemm_dual<<<gemm_blocks, 256, 0, stream>>>(node_fts, Wl1, bl1, Wr1, br1, xl, xr);
  gat_gather<<<gather_blocks, 256, 0, stream>>>(xl, xr, row_start, csr_src, att1, bias1, h);

  // ---- layer 2 ----
  gemm_dual<<<gemm_blocks, 256, 0, stream>>>(h, Wl2, bl2, Wr2, br2, xl, xr);
  gat_gather<<<gather_blocks, 256, 0, stream>>>(xl, xr, row_start, csr_src, att2, bias2, (float*)d_out);
}